// Round 5
// baseline (461.065 us; speedup 1.0000x reference)
//
#include <hip/hip_runtime.h>
#include <stdint.h>

// Problem constants (fixed by reference setup_inputs)
constexpr int N    = 8192;
constexpr int D    = 512;
constexpr int KEXT = 8;
constexpr int NCLS = 1000;
#define TAU_INV  14.285714285714285714f   // 1/0.07
#define SQRT_TI  3.7796447300922722f      // sqrt(1/0.07); folded into packed f16

typedef _Float16 half8 __attribute__((ext_vector_type(8)));
typedef float    f32x4 __attribute__((ext_vector_type(4)));

typedef __attribute__((address_space(1))) void gvoid;
typedef __attribute__((address_space(3))) void lvoid;

// ---------------- fused prep: histogram + fragment-packing of q ------------
// qf layout (validated R4, absmax 0.0): fragment (t, ks), t in [0,512) 16-row
// tile, ks in [0,16) 32-col K-step, is a contiguous 1KB block; half8 slot
// (t*16+ks)*64 + lane holds q[t*16+(lane&15)][ks*32+(lane>>4)*8 ..+8]*SQRT_TI.
// Also emits invy[j] = 1/count[y[j]] so gemm never gathers invc.
__global__ void prep_k(const float* __restrict__ q, const int* __restrict__ y,
                       _Float16* __restrict__ qf, int* __restrict__ counts,
                       float* __restrict__ invy, float* __restrict__ pos,
                       float* __restrict__ neg, float* __restrict__ out) {
    const int b = blockIdx.x, tid = threadIdx.x;
    if (b == 0) {
        __shared__ int h[NCLS];
        for (int i = tid; i < NCLS; i += 256) h[i] = 0;
        __syncthreads();
        for (int i = tid; i < N; i += 256) atomicAdd(&h[y[i]], 1);
        __syncthreads();
        for (int i = tid; i < NCLS; i += 256) counts[i] = h[i];
        if (tid == 0) out[0] = 0.f;
        __syncthreads();
        for (int i = tid; i < N; i += 256) invy[i] = 1.0f / (float)h[y[i]];
        return;
    }
    const int gid = (b - 1) * 256 + tid;     // over N*64 8-float groups
    const int row = gid >> 6;                // source row of q
    const int cg  = gid & 63;                // 8-float group within the row
    const float4* src = reinterpret_cast<const float4*>(q + (size_t)row * D + cg * 8);
    float4 v0 = src[0], v1 = src[1];         // coalesced: 64 lanes = full row
    half8 o;
    o[0] = (_Float16)(v0.x * SQRT_TI); o[1] = (_Float16)(v0.y * SQRT_TI);
    o[2] = (_Float16)(v0.z * SQRT_TI); o[3] = (_Float16)(v0.w * SQRT_TI);
    o[4] = (_Float16)(v1.x * SQRT_TI); o[5] = (_Float16)(v1.y * SQRT_TI);
    o[6] = (_Float16)(v1.z * SQRT_TI); o[7] = (_Float16)(v1.w * SQRT_TI);
    const int t = row >> 4, l15 = row & 15, ks = cg >> 2, quad = cg & 3;
    reinterpret_cast<half8*>(qf)[(size_t)(t * 16 + ks) * 64 + quad * 16 + l15] = o;
    if (gid < N) { pos[gid] = 0.f; neg[gid] = 0.f; }
}

// ---------------- stripe-sweep GEMM (q @ q^T) + fused contrastive epilogue -
// 256 blocks x 512 threads. Block = 128-row i-band x 2048-col j-stripe.
// stripe = b&3 -> each XCD (b%8) sees ONE stripe: its 2MB B-set stays L2-hot.
// A-band (128KB packed fragments) DMA'd linearly to LDS once; single barrier.
// 8 waves 2x4, wave tile 64x64 (4 A-frags from LDS, 4 B-frags from global),
// row pos/neg sums live in registers across the 8-j-tile sweep; 1 atomic/row.
__global__ __launch_bounds__(512, 2) void gemm_k(
        const _Float16* __restrict__ qf,
        const int* __restrict__ y,
        const float* __restrict__ invy,
        float* __restrict__ pos_sum,
        float* __restrict__ neg_sum) {
    __shared__ _Float16 Asl[N == 0 ? 1 : 128 * 512];   // 128 KB packed A-band

    const int tid  = threadIdx.x;
    const int wave = tid >> 6;
    const int lane = tid & 63;
    const int quad = lane >> 4;
    const int l15  = lane & 15;

    const int b      = blockIdx.x;
    const int stripe = b & 3;          // XCD (b%8) -> stripe (b%8)&3: 1 per XCD
    const int ib     = b >> 2;         // i-band 0..63
    const int ibase  = ib * 128;
    const int jstart = stripe * 2048;

    // ---- DMA A-band into LDS: pure linear copy (fragment-major layout) ----
    {
        const char* src = (const char*)qf + (size_t)ib * 131072 + wave * 16384;
        char*       dst = (char*)Asl + wave * 16384;
#pragma unroll
        for (int i = 0; i < 16; i++)
            __builtin_amdgcn_global_load_lds((gvoid*)(src + i * 1024 + lane * 16),
                                             (lvoid*)(dst + i * 1024 + lane * 16), 16, 0, 0);
    }

    // wave position: 2 row-groups x 4 col-groups
    const int wr = (wave >> 2) * 64;   // 0 or 64 within i-band
    const int wc = (wave & 3) * 64;    // 0..192 within 256-wide j-tile

    // per-lane row metadata (row = wr + mi*16 + quad*4 + r)
    int   yi[16];
#pragma unroll
    for (int mi = 0; mi < 4; mi++)
#pragma unroll
        for (int r = 0; r < 4; r++)
            yi[mi * 4 + r] = y[ibase + wr + mi * 16 + quad * 4 + r];

    float posp[16], negp[16];
#pragma unroll
    for (int e = 0; e < 16; e++) { posp[e] = 0.f; negp[e] = 0.f; }

    __syncthreads();   // A-band resident (compiler drains vmcnt before barrier)

    const half8* fb = reinterpret_cast<const half8*>(qf);

    for (int jt = 0; jt < 8; jt++) {
        const int j0 = jstart + jt * 256;

        // column metadata for this tile (4 B-frags x 16 cols)
        int   yjv[4];
        float icj[4];
#pragma unroll
        for (int mj = 0; mj < 4; mj++) {
            int jc = j0 + wc + mj * 16 + l15;
            yjv[mj] = y[jc];
            icj[mj] = invy[jc];
        }

        f32x4 acc[4][4];
#pragma unroll
        for (int a = 0; a < 4; a++)
#pragma unroll
            for (int c = 0; c < 4; c++) acc[a][c] = (f32x4)0.0f;

        const int tjbase = (j0 + wc) >> 4;     // global 16-col fragment index
#pragma unroll
        for (int ks = 0; ks < 16; ks++) {
            half8 af[4], bf[4];
#pragma unroll
            for (int mi = 0; mi < 4; mi++) {
                int tl = (wr >> 4) + mi;       // local A fragment row
                af[mi] = *reinterpret_cast<const half8*>(
                    (const char*)Asl + ((tl * 16 + ks) * 64 + lane) * 16);
            }
#pragma unroll
            for (int mj = 0; mj < 4; mj++)
                bf[mj] = fb[(size_t)((tjbase + mj) * 16 + ks) * 64 + lane];
#pragma unroll
            for (int mi = 0; mi < 4; mi++)
#pragma unroll
                for (int mj = 0; mj < 4; mj++)
                    acc[mi][mj] = __builtin_amdgcn_mfma_f32_16x16x32_f16(af[mi], bf[mj], acc[mi][mj], 0, 0, 0);
        }

        // fused epilogue: acc already holds sim/tau (sqrt(1/tau) folded in qf)
#pragma unroll
        for (int mi = 0; mi < 4; mi++) {
#pragma unroll
            for (int r = 0; r < 4; r++) {
                const int e    = mi * 4 + r;
                const int irow = ibase + wr + mi * 16 + quad * 4 + r;
                const int myi  = yi[e];
                float ps = 0.f, ns = 0.f;
#pragma unroll
                for (int mj = 0; mj < 4; mj++) {
                    const int jcol = j0 + wc + mj * 16 + l15;   // C/D: col = lane&15
                    float a    = acc[mi][mj][r];
                    float ex   = __expf(a);
                    bool  nz   = (a != 0.0f);                   // faithful masked_fill(x==0,-inf)
                    bool  same = (myi == yjv[mj]);
                    ps += (same && (irow != jcol) && nz) ? ex : 0.0f;
                    ns += (!same && nz) ? ex * icj[mj] : 0.0f;
                }
                posp[e] += ps;
                negp[e] += ns;
            }
        }
    }

    // ---- commit: reduce over the 16 cols held per quad, 1 atomic per row ----
#pragma unroll
    for (int mi = 0; mi < 4; mi++) {
#pragma unroll
        for (int r = 0; r < 4; r++) {
            const int e = mi * 4 + r;
            float ps = posp[e], ns = negp[e];
#pragma unroll
            for (int off = 1; off < 16; off <<= 1) {
                ps += __shfl_xor(ps, off);
                ns += __shfl_xor(ns, off);
            }
            if (l15 == 0) {
                const int irow = ibase + wr + mi * 16 + quad * 4 + r;
                atomicAdd(&pos_sum[irow], ps);
                atomicAdd(&neg_sum[irow], ns);
            }
        }
    }
}

// ---------------- finalize: k_sims (fp32) + log ratio + fused mean ----------
__global__ void finalize_k(const float* __restrict__ q, const float* __restrict__ kmat,
                           const int* __restrict__ y, const int* __restrict__ counts,
                           const float* __restrict__ pos_sum, const float* __restrict__ neg_sum,
                           float* __restrict__ out) {
    __shared__ float part[4];
    const int wave = threadIdx.x >> 6, lane = threadIdx.x & 63;
    const int i = blockIdx.x * 4 + wave;

    const float4* q4 = reinterpret_cast<const float4*>(q) + (size_t)i * 128;
    const float4* k4 = reinterpret_cast<const float4*>(kmat) + (size_t)i * KEXT * 128;
    float4 qa = q4[lane], qb = q4[lane + 64];

    float esum = 0.f;
    for (int kk = 0; kk < KEXT; kk++) {
        float4 ka = k4[(size_t)kk * 128 + lane];
        float4 kb = k4[(size_t)kk * 128 + lane + 64];
        float p = qa.x * ka.x;
        p = fmaf(qa.y, ka.y, p); p = fmaf(qa.z, ka.z, p); p = fmaf(qa.w, ka.w, p);
        p = fmaf(qb.x, kb.x, p); p = fmaf(qb.y, kb.y, p);
        p = fmaf(qb.z, kb.z, p); p = fmaf(qb.w, kb.w, p);
#pragma unroll
        for (int off = 1; off < 64; off <<= 1) p += __shfl_xor(p, off);
        esum += __expf(p * TAU_INV);
    }
    if (lane == 0) {
        float num = logf(esum + pos_sum[i]);
        float den = logf(neg_sum[i]);
        float cnt = (float)(counts[y[i]] - 1 + KEXT);  // same_class_counts, label-only
        part[wave] = -(num - den) / (cnt * (float)N);
    }
    __syncthreads();
    if (threadIdx.x == 0)
        atomicAdd(out, part[0] + part[1] + part[2] + part[3]);
}

// ---------------- launch ----------------
extern "C" void kernel_launch(void* const* d_in, const int* in_sizes, int n_in,
                              void* d_out, int out_size, void* d_ws, size_t ws_size,
                              hipStream_t stream) {
    const float* q    = (const float*)d_in[0];
    const float* kmat = (const float*)d_in[1];
    const int*   y    = (const int*)d_in[2];
    float* out = (float*)d_out;

    char* ws = (char*)d_ws;
    _Float16* qf   = (_Float16*)ws;                 // 8 MB: packed fragments
    int*   counts  = (int*)  (ws + 8388608);        // 1000 ints
    float* invy    = (float*)(ws + 8392704);        // N floats: 1/count[y[j]]
    float* pos     = (float*)(ws + 8425472);        // N floats
    float* neg     = (float*)(ws + 8458240);        // N floats

    prep_k    <<<1 + (N * 64) / 256, 256, 0, stream>>>(q, y, qf, counts, invy, pos, neg, out);
    gemm_k    <<<256, 512, 0, stream>>>(qf, y, invy, pos, neg);
    finalize_k<<<N / 4, 256, 0, stream>>>(q, kmat, y, counts, pos, neg, out);
}

// Round 6
// 360.440 us; speedup vs baseline: 1.2792x; 1.2792x over previous
//
#include <hip/hip_runtime.h>
#include <stdint.h>

// Problem constants (fixed by reference setup_inputs)
constexpr int N    = 8192;
constexpr int D    = 512;
constexpr int KEXT = 8;
constexpr int NCLS = 1000;
#define TAU_INV  14.285714285714285714f   // 1/0.07
#define SQRT_TI  3.7796447300922722f      // sqrt(1/0.07); folded into packed f16

constexpr int BM = 128, BN = 128;
constexpr int NB   = N / BM;             // 64 tile-rows
constexpr int NBLK = NB * (NB + 1) / 2;  // 2080 upper-tri tiles

typedef _Float16 half8 __attribute__((ext_vector_type(8)));
typedef float    f32x4 __attribute__((ext_vector_type(4)));

// ---------------- fused prep: histogram + fragment-packing of q ------------
// qf layout (validated R4/R5, absmax 0.0): fragment (t, ks), t in [0,512)
// 16-row tile, ks in [0,16) 32-col K-step, is a contiguous 1KB block; half8
// slot (t*16+ks)*64 + lane holds q[t*16+(lane&15)][ks*32+(lane>>4)*8..+8]*SQRT_TI.
__global__ void prep_k(const float* __restrict__ q, const int* __restrict__ y,
                       _Float16* __restrict__ qf, int* __restrict__ counts,
                       float* __restrict__ invc, float* __restrict__ pos,
                       float* __restrict__ neg) {
    const int b = blockIdx.x, tid = threadIdx.x;
    if (b == 0) {
        __shared__ int h[NCLS];
        for (int i = tid; i < NCLS; i += 256) h[i] = 0;
        __syncthreads();
        for (int i = tid; i < N; i += 256) atomicAdd(&h[y[i]], 1);
        __syncthreads();
        for (int i = tid; i < NCLS; i += 256) {
            int c = h[i];
            counts[i] = c;
            invc[i]   = 1.0f / (float)c;     // classes with count 0 never indexed
        }
        return;
    }
    const int gid = (b - 1) * 256 + tid;     // over N*64 8-float groups
    const int row = gid >> 6;                // source row of q
    const int cg  = gid & 63;                // 8-float group within the row
    const float4* src = reinterpret_cast<const float4*>(q + (size_t)row * D + cg * 8);
    float4 v0 = src[0], v1 = src[1];         // coalesced: 64 lanes = full row
    half8 o;
    o[0] = (_Float16)(v0.x * SQRT_TI); o[1] = (_Float16)(v0.y * SQRT_TI);
    o[2] = (_Float16)(v0.z * SQRT_TI); o[3] = (_Float16)(v0.w * SQRT_TI);
    o[4] = (_Float16)(v1.x * SQRT_TI); o[5] = (_Float16)(v1.y * SQRT_TI);
    o[6] = (_Float16)(v1.z * SQRT_TI); o[7] = (_Float16)(v1.w * SQRT_TI);
    const int t = row >> 4, l15 = row & 15, ks = cg >> 2, quad = cg & 3;
    reinterpret_cast<half8*>(qf)[(size_t)(t * 16 + ks) * 64 + quad * 16 + l15] = o;
    if (gid < N) { pos[gid] = 0.f; neg[gid] = 0.f; }
}

// ---------------- fused symmetric GEMM (q @ q^T) + contrastive epilogue ----
// R4 structure (best measured: coalesced packed-fragment direct loads, zero
// K-loop barriers, triangular tiles) + explicit register double-buffered
// K-pipeline: stage ks+1's 8 fragment loads issue BEFORE stage ks's MFMAs,
// so each wave always has ~8 KB of loads in flight (fine-grained vmcnt).
__global__ __launch_bounds__(256, 2) void gemm_k(
        const _Float16* __restrict__ qf,
        const int* __restrict__ y,
        const float* __restrict__ invc,
        float* __restrict__ pos_sum,
        float* __restrict__ neg_sum) {
    __shared__ int   yis[BM];
    __shared__ int   yjs[BN];
    __shared__ float icsA[BM];
    __shared__ float icsB[BN];

    const int tid  = threadIdx.x;
    const int wave = tid >> 6;
    const int lane = tid & 63;
    const int quad = lane >> 4;
    const int l15  = lane & 15;

    // ---- tile index: XCD-contiguous bands (8 XCDs round-robin on blockIdx) ----
    const int t0 = blockIdx.x;
    const int t  = (t0 & 7) * (NBLK / 8) + (t0 >> 3);   // NBLK/8 = 260 exact

    // ---- decode upper-triangular tile (bi <= bj) ----
    int bi = (int)(((float)(2 * NB + 1) -
                    sqrtf((float)((2 * NB + 1) * (2 * NB + 1)) - 8.0f * (float)t)) * 0.5f);
    if (bi < 0) bi = 0;
    if (bi > NB - 1) bi = NB - 1;
    while ((bi + 1) * NB - ((bi + 1) * bi >> 1) <= t) ++bi;
    while (bi * NB - (bi * (bi - 1) >> 1) > t) --bi;
    const int bj = bi + (t - (bi * NB - (bi * (bi - 1) >> 1)));
    const int ibase = bi * BM, jbase = bj * BN;

    if (tid < BM) {
        int yi = y[ibase + tid];
        int yj = y[jbase + tid];
        yis[tid] = yi;  icsA[tid] = invc[yi];
        yjs[tid] = yj;  icsB[tid] = invc[yj];
    }
    __syncthreads();   // only barrier in the kernel

    // wave position within the 128x128 tile (2x2 waves of 64x64)
    const int wr = (wave >> 1) * 64;
    const int wc = (wave & 1) * 64;

    f32x4 acc[4][4];
#pragma unroll
    for (int a = 0; a < 4; a++)
#pragma unroll
        for (int b = 0; b < 4; b++) acc[a][b] = (f32x4)0.0f;

    // fragment-block pointers: tile index = base/16 + m; +lane gives this
    // lane's 16B slot; K-step advances by 64 half8 slots (1KB)
    const half8* fb = reinterpret_cast<const half8*>(qf);
    const half8* pA[4];
    const half8* pB[4];
#pragma unroll
    for (int m = 0; m < 4; m++) {
        pA[m] = fb + (size_t)((bi * 8) + (wr >> 4) + m) * 1024 + lane;
        pB[m] = fb + (size_t)((bj * 8) + (wc >> 4) + m) * 1024 + lane;
    }

    // ---- software-pipelined K-loop: register double-buffer, depth 1 ----
    half8 af[2][4], bf[2][4];
#pragma unroll
    for (int m = 0; m < 4; m++) { af[0][m] = pA[m][0]; bf[0][m] = pB[m][0]; }

#pragma unroll
    for (int ks = 0; ks < 16; ks++) {
        const int cur = ks & 1, nxt = cur ^ 1;
        if (ks < 15) {
#pragma unroll
            for (int m = 0; m < 4; m++) {
                af[nxt][m] = pA[m][(ks + 1) * 64];
                bf[nxt][m] = pB[m][(ks + 1) * 64];
            }
        }
#pragma unroll
        for (int mi = 0; mi < 4; mi++)
#pragma unroll
            for (int mj = 0; mj < 4; mj++)
                acc[mi][mj] = __builtin_amdgcn_mfma_f32_16x16x32_f16(af[cur][mi], bf[cur][mj], acc[mi][mj], 0, 0, 0);
    }

    // ---- epilogue: masked exp + row/col reductions ----
    // acc already holds sim/tau thanks to the sqrt(1/tau) folded into qf.
    int   yjv[4];
    float icj[4];
#pragma unroll
    for (int mj = 0; mj < 4; mj++) {
        int jl = wc + mj * 16 + l15;
        yjv[mj] = yjs[jl];
        icj[mj] = icsB[jl];
    }

    if (bi == bj) {
        // diagonal tile: both orders of each pair are in-tile; row-side only
#pragma unroll
        for (int mi = 0; mi < 4; mi++) {
#pragma unroll
            for (int r = 0; r < 4; r++) {
                const int il   = wr + mi * 16 + quad * 4 + r;   // C/D: row = quad*4+reg
                const int irow = ibase + il;
                const int yi   = yis[il];
                float posp = 0.f, negp = 0.f;
#pragma unroll
                for (int mj = 0; mj < 4; mj++) {
                    const int jcol = jbase + wc + mj * 16 + l15; // C/D: col = lane&15
                    float a    = acc[mi][mj][r];
                    float e    = __expf(a);
                    bool  nz   = (a != 0.0f);                    // faithful masked_fill(x==0,-inf)
                    bool  same = (yi == yjv[mj]);
                    posp += (same && (irow != jcol) && nz) ? e : 0.0f;
                    negp += (!same && nz) ? e * icj[mj] : 0.0f;
                }
#pragma unroll
                for (int off = 1; off < 16; off <<= 1) {
                    posp += __shfl_xor(posp, off);
                    negp += __shfl_xor(negp, off);
                }
                if (l15 == 0) {
                    atomicAdd(&pos_sum[irow], posp);
                    atomicAdd(&neg_sum[irow], negp);
                }
            }
        }
    } else {
        // off-diagonal tile: each element (i,j) serves both (i,j) and (j,i)
        float cp[4] = {0.f, 0.f, 0.f, 0.f};
        float cn[4] = {0.f, 0.f, 0.f, 0.f};
#pragma unroll
        for (int mi = 0; mi < 4; mi++) {
#pragma unroll
            for (int r = 0; r < 4; r++) {
                const int il   = wr + mi * 16 + quad * 4 + r;
                const int irow = ibase + il;
                const int yi   = yis[il];
                const float ici = icsA[il];
                float posp = 0.f, negp = 0.f;
#pragma unroll
                for (int mj = 0; mj < 4; mj++) {
                    float a    = acc[mi][mj][r];
                    float e    = __expf(a);
                    bool  nz   = (a != 0.0f);
                    bool  same = (yi == yjv[mj]);
                    float pe   = (same && nz) ? e : 0.0f;        // i != j guaranteed (bi<bj)
                    posp   += pe;
                    cp[mj] += pe;
                    negp   += (!same && nz) ? e * icj[mj] : 0.0f;
                    cn[mj] += (!same && nz) ? e * ici : 0.0f;
                }
#pragma unroll
                for (int off = 1; off < 16; off <<= 1) {
                    posp += __shfl_xor(posp, off);
                    negp += __shfl_xor(negp, off);
                }
                if (l15 == 0) {
                    atomicAdd(&pos_sum[irow], posp);
                    atomicAdd(&neg_sum[irow], negp);
                }
            }
        }
        // column-side: reduce across the 4 quads (rows), lanes quad==0 commit
#pragma unroll
        for (int mj = 0; mj < 4; mj++) {
            float a = cp[mj], b = cn[mj];
            a += __shfl_xor(a, 16); a += __shfl_xor(a, 32);
            b += __shfl_xor(b, 16); b += __shfl_xor(b, 32);
            if (quad == 0) {
                const int jcol = jbase + wc + mj * 16 + l15;
                atomicAdd(&pos_sum[jcol], a);
                atomicAdd(&neg_sum[jcol], b);
            }
        }
    }
}

// ---------------- per-row finalize: k_sims (fp32, float4 loads) ------------
__global__ void finalize_k(const float* __restrict__ q, const float* __restrict__ kmat,
                           const int* __restrict__ y, const int* __restrict__ counts,
                           const float* __restrict__ pos_sum, const float* __restrict__ neg_sum,
                           float* __restrict__ loss) {
    const int wave = threadIdx.x >> 6, lane = threadIdx.x & 63;
    const int i = blockIdx.x * 4 + wave;

    const float4* q4 = reinterpret_cast<const float4*>(q) + (size_t)i * 128;
    const float4* k4 = reinterpret_cast<const float4*>(kmat) + (size_t)i * KEXT * 128;
    float4 qa = q4[lane], qb = q4[lane + 64];

    float esum = 0.f;
    for (int kk = 0; kk < KEXT; kk++) {
        float4 ka = k4[(size_t)kk * 128 + lane];
        float4 kb = k4[(size_t)kk * 128 + lane + 64];
        float p = qa.x * ka.x;
        p = fmaf(qa.y, ka.y, p); p = fmaf(qa.z, ka.z, p); p = fmaf(qa.w, ka.w, p);
        p = fmaf(qb.x, kb.x, p); p = fmaf(qb.y, kb.y, p);
        p = fmaf(qb.z, kb.z, p); p = fmaf(qb.w, kb.w, p);
#pragma unroll
        for (int off = 1; off < 64; off <<= 1) p += __shfl_xor(p, off);
        esum += __expf(p * TAU_INV);
    }
    if (lane == 0) {
        float num = logf(esum + pos_sum[i]);
        float den = logf(neg_sum[i]);
        float cnt = (float)(counts[y[i]] - 1 + KEXT);  // same_class_counts, label-only
        loss[i] = -(num - den) / cnt;
    }
}

__global__ void reduce_k(const float* __restrict__ loss, float* __restrict__ out) {
    __shared__ float part[16];
    int tid = threadIdx.x;   // 1024 threads
    float s = 0.f;
    for (int i = tid; i < N; i += 1024) s += loss[i];
#pragma unroll
    for (int off = 1; off < 64; off <<= 1) s += __shfl_xor(s, off);
    if ((tid & 63) == 0) part[tid >> 6] = s;
    __syncthreads();
    if (tid < 16) {
        float v = part[tid];
#pragma unroll
        for (int off = 1; off < 16; off <<= 1) v += __shfl_xor(v, off);
        if (tid == 0) out[0] = v / (float)N;
    }
}

// ---------------- launch ----------------
extern "C" void kernel_launch(void* const* d_in, const int* in_sizes, int n_in,
                              void* d_out, int out_size, void* d_ws, size_t ws_size,
                              hipStream_t stream) {
    const float* q    = (const float*)d_in[0];
    const float* kmat = (const float*)d_in[1];
    const int*   y    = (const int*)d_in[2];
    float* out = (float*)d_out;

    char* ws = (char*)d_ws;
    _Float16* qf   = (_Float16*)ws;                 // 8 MB: packed fragments
    int*   counts  = (int*)  (ws + 8388608);        // 1000 ints
    float* invc    = (float*)(ws + 8392704);        // 1000 floats
    float* pos     = (float*)(ws + 8396800);        // N floats
    float* neg     = (float*)(ws + 8429568);        // N floats
    float* loss    = (float*)(ws + 8462336);        // N floats

    prep_k    <<<1 + (N * 64) / 256, 256, 0, stream>>>(q, y, qf, counts, invc, pos, neg);
    gemm_k    <<<NBLK, 256, 0, stream>>>(qf, y, invc, pos, neg);
    finalize_k<<<N / 4, 256, 0, stream>>>(q, kmat, y, counts, pos, neg, loss);
    reduce_k  <<<1, 1024, 0, stream>>>(loss, out);
}

// Round 7
// 354.181 us; speedup vs baseline: 1.3018x; 1.0177x over previous
//
#include <hip/hip_runtime.h>
#include <hip/hip_fp8.h>
#include <stdint.h>

// Problem constants (fixed by reference setup_inputs)
constexpr int N    = 8192;
constexpr int D    = 512;
constexpr int KEXT = 8;
constexpr int NCLS = 1000;
#define TAU_INV  14.285714285714285714f   // 1/0.07
#define SQRT_TI  3.7796447300922722f      // sqrt(1/0.07); folded into packed fp8

constexpr int BM = 128, BN = 128;
constexpr int NB   = N / BM;             // 64 tile-rows
constexpr int NBLK = NB * (NB + 1) / 2;  // 2080 upper-tri tiles

typedef long   long2_t __attribute__((ext_vector_type(2)));  // 16B = 2 fp8 MFMA operands
typedef float  f32x4   __attribute__((ext_vector_type(4)));

__device__ __forceinline__ uint32_t pack4_e4m3(float a, float b, float c, float d) {
    __hip_fp8_e4m3 A(a), B(b), C(c), D(d);   // OCP e4m3fn on gfx950
    return (uint32_t)A.__x | ((uint32_t)B.__x << 8) |
           ((uint32_t)C.__x << 16) | ((uint32_t)D.__x << 24);
}

// ---------------- fused prep: histogram + fp8 fragment-packing of q --------
// qf8 layout: 16B granule slot = (t*512 + ks2*64 + lane), t=16-row tile,
// ks2=K-macrostep (64 wide), lane=quad*16+l15. Granule bytes [0..8) hold
// q[t*16+l15][ks2*64+quad*8 ..+8)*SQRT_TI, bytes [8..16) the +32 window —
// i.e. one dwordx4 load feeds BOTH MFMAs of the 64-wide K-macrostep.
// A/B use identical packing => any k-permutation error cancels in a.b.
__global__ void prep_k(const float* __restrict__ q, const int* __restrict__ y,
                       uint32_t* __restrict__ qf8, int* __restrict__ counts,
                       float* __restrict__ invc, float* __restrict__ pos,
                       float* __restrict__ neg) {
    const int b = blockIdx.x, tid = threadIdx.x;
    if (b == 0) {
        __shared__ int h[NCLS];
        for (int i = tid; i < NCLS; i += 256) h[i] = 0;
        __syncthreads();
        for (int i = tid; i < N; i += 256) atomicAdd(&h[y[i]], 1);
        __syncthreads();
        for (int i = tid; i < NCLS; i += 256) {
            int c = h[i];
            counts[i] = c;
            invc[i]   = 1.0f / (float)c;     // classes with count 0 never indexed
        }
        return;
    }
    const int gid = (b - 1) * 256 + tid;     // over N*32 granules
    const int row = gid >> 5;                // source row of q
    const int c   = gid & 31;                // granule within row
    const int ks2 = c >> 2, quad = c & 3;
    const float* src = q + (size_t)row * D + ks2 * 64 + quad * 8;
    float4 v0 = *reinterpret_cast<const float4*>(src);
    float4 v1 = *reinterpret_cast<const float4*>(src + 4);
    float4 v2 = *reinterpret_cast<const float4*>(src + 32);
    float4 v3 = *reinterpret_cast<const float4*>(src + 36);
    uint4 o;
    o.x = pack4_e4m3(v0.x * SQRT_TI, v0.y * SQRT_TI, v0.z * SQRT_TI, v0.w * SQRT_TI);
    o.y = pack4_e4m3(v1.x * SQRT_TI, v1.y * SQRT_TI, v1.z * SQRT_TI, v1.w * SQRT_TI);
    o.z = pack4_e4m3(v2.x * SQRT_TI, v2.y * SQRT_TI, v2.z * SQRT_TI, v2.w * SQRT_TI);
    o.w = pack4_e4m3(v3.x * SQRT_TI, v3.y * SQRT_TI, v3.z * SQRT_TI, v3.w * SQRT_TI);
    const int t = row >> 4, l15 = row & 15;
    reinterpret_cast<uint4*>(qf8)[(size_t)t * 512 + ks2 * 64 + quad * 16 + l15] = o;
    if (gid < N) { pos[gid] = 0.f; neg[gid] = 0.f; }
}

// ---------------- fused symmetric GEMM (q @ q^T) + contrastive epilogue ----
// R4 structure (coalesced packed-fragment direct loads, zero K-loop barriers,
// triangular tiles) with fp8 operands: half the bytes AND half the load
// count of the f16 version (16B granule feeds 2 MFMAs). Band-major tile
// order for temporal A-band locality.
__global__ __launch_bounds__(256, 3) void gemm_k(
        const uint32_t* __restrict__ qf8,
        const int* __restrict__ y,
        const float* __restrict__ invc,
        float* __restrict__ pos_sum,
        float* __restrict__ neg_sum) {
    __shared__ int   yis[BM];
    __shared__ int   yjs[BN];
    __shared__ float icsA[BM];
    __shared__ float icsB[BN];

    const int tid  = threadIdx.x;
    const int wave = tid >> 6;
    const int lane = tid & 63;
    const int quad = lane >> 4;
    const int l15  = lane & 15;

    // ---- decode upper-triangular tile (bi <= bj), band-major order ----
    const int t = blockIdx.x;
    int bi = (int)(((float)(2 * NB + 1) -
                    sqrtf((float)((2 * NB + 1) * (2 * NB + 1)) - 8.0f * (float)t)) * 0.5f);
    if (bi < 0) bi = 0;
    if (bi > NB - 1) bi = NB - 1;
    while ((bi + 1) * NB - ((bi + 1) * bi >> 1) <= t) ++bi;
    while (bi * NB - (bi * (bi - 1) >> 1) > t) --bi;
    const int bj = bi + (t - (bi * NB - (bi * (bi - 1) >> 1)));
    const int ibase = bi * BM, jbase = bj * BN;

    if (tid < BM) {
        int yi = y[ibase + tid];
        int yj = y[jbase + tid];
        yis[tid] = yi;  icsA[tid] = invc[yi];
        yjs[tid] = yj;  icsB[tid] = invc[yj];
    }
    __syncthreads();   // only barrier in the kernel

    // wave position within the 128x128 tile (2x2 waves of 64x64)
    const int wr = (wave >> 1) * 64;
    const int wc = (wave & 1) * 64;

    f32x4 acc[4][4];
#pragma unroll
    for (int a = 0; a < 4; a++)
#pragma unroll
        for (int b = 0; b < 4; b++) acc[a][b] = (f32x4)0.0f;

    // fragment pointers: 16-row tile tA -> slots tA*512 + ks2*64 + lane
    const long2_t* fb = reinterpret_cast<const long2_t*>(qf8);
    const long2_t* pA[4];
    const long2_t* pB[4];
#pragma unroll
    for (int m = 0; m < 4; m++) {
        pA[m] = fb + (size_t)(bi * 8 + (wr >> 4) + m) * 512 + lane;
        pB[m] = fb + (size_t)(bj * 8 + (wc >> 4) + m) * 512 + lane;
    }

    // ---- K-loop: 8 macro-steps of K=64, register double-buffered ----
    long2_t af[2][4], bf[2][4];
#pragma unroll
    for (int m = 0; m < 4; m++) { af[0][m] = pA[m][0]; bf[0][m] = pB[m][0]; }

#pragma unroll
    for (int ks2 = 0; ks2 < 8; ks2++) {
        const int cur = ks2 & 1, nxt = cur ^ 1;
        if (ks2 < 7) {
#pragma unroll
            for (int m = 0; m < 4; m++) {
                af[nxt][m] = pA[m][(ks2 + 1) * 64];
                bf[nxt][m] = pB[m][(ks2 + 1) * 64];
            }
        }
#pragma unroll
        for (int mi = 0; mi < 4; mi++)
#pragma unroll
            for (int mj = 0; mj < 4; mj++)
                acc[mi][mj] = __builtin_amdgcn_mfma_f32_16x16x32_fp8_fp8(
                    af[cur][mi].x, bf[cur][mj].x, acc[mi][mj], 0, 0, 0);
#pragma unroll
        for (int mi = 0; mi < 4; mi++)
#pragma unroll
            for (int mj = 0; mj < 4; mj++)
                acc[mi][mj] = __builtin_amdgcn_mfma_f32_16x16x32_fp8_fp8(
                    af[cur][mi].y, bf[cur][mj].y, acc[mi][mj], 0, 0, 0);
    }

    // ---- epilogue: masked exp + row/col reductions ----
    // acc already holds sim/tau (sqrt(1/tau) folded into the fp8 pack).
    int   yjv[4];
    float icj[4];
#pragma unroll
    for (int mj = 0; mj < 4; mj++) {
        int jl = wc + mj * 16 + l15;
        yjv[mj] = yjs[jl];
        icj[mj] = icsB[jl];
    }

    if (bi == bj) {
        // diagonal tile: both orders of each pair are in-tile; row-side only
#pragma unroll
        for (int mi = 0; mi < 4; mi++) {
#pragma unroll
            for (int r = 0; r < 4; r++) {
                const int il   = wr + mi * 16 + quad * 4 + r;   // C/D: row = quad*4+reg
                const int irow = ibase + il;
                const int yi   = yis[il];
                float posp = 0.f, negp = 0.f;
#pragma unroll
                for (int mj = 0; mj < 4; mj++) {
                    const int jcol = jbase + wc + mj * 16 + l15; // C/D: col = lane&15
                    float a    = acc[mi][mj][r];
                    float e    = __expf(a);
                    bool  nz   = (a != 0.0f);                    // faithful masked_fill(x==0,-inf)
                    bool  same = (yi == yjv[mj]);
                    posp += (same && (irow != jcol) && nz) ? e : 0.0f;
                    negp += (!same && nz) ? e * icj[mj] : 0.0f;
                }
#pragma unroll
                for (int off = 1; off < 16; off <<= 1) {
                    posp += __shfl_xor(posp, off);
                    negp += __shfl_xor(negp, off);
                }
                if (l15 == 0) {
                    atomicAdd(&pos_sum[irow], posp);
                    atomicAdd(&neg_sum[irow], negp);
                }
            }
        }
    } else {
        // off-diagonal tile: each element (i,j) serves both (i,j) and (j,i)
        float cp[4] = {0.f, 0.f, 0.f, 0.f};
        float cn[4] = {0.f, 0.f, 0.f, 0.f};
#pragma unroll
        for (int mi = 0; mi < 4; mi++) {
#pragma unroll
            for (int r = 0; r < 4; r++) {
                const int il   = wr + mi * 16 + quad * 4 + r;
                const int irow = ibase + il;
                const int yi   = yis[il];
                const float ici = icsA[il];
                float posp = 0.f, negp = 0.f;
#pragma unroll
                for (int mj = 0; mj < 4; mj++) {
                    float a    = acc[mi][mj][r];
                    float e    = __expf(a);
                    bool  nz   = (a != 0.0f);
                    bool  same = (yi == yjv[mj]);
                    float pe   = (same && nz) ? e : 0.0f;        // i != j guaranteed (bi<bj)
                    posp   += pe;
                    cp[mj] += pe;
                    negp   += (!same && nz) ? e * icj[mj] : 0.0f;
                    cn[mj] += (!same && nz) ? e * ici : 0.0f;
                }
#pragma unroll
                for (int off = 1; off < 16; off <<= 1) {
                    posp += __shfl_xor(posp, off);
                    negp += __shfl_xor(negp, off);
                }
                if (l15 == 0) {
                    atomicAdd(&pos_sum[irow], posp);
                    atomicAdd(&neg_sum[irow], negp);
                }
            }
        }
        // column-side: reduce across the 4 quads (rows), lanes quad==0 commit
#pragma unroll
        for (int mj = 0; mj < 4; mj++) {
            float a = cp[mj], b = cn[mj];
            a += __shfl_xor(a, 16); a += __shfl_xor(a, 32);
            b += __shfl_xor(b, 16); b += __shfl_xor(b, 32);
            if (quad == 0) {
                const int jcol = jbase + wc + mj * 16 + l15;
                atomicAdd(&pos_sum[jcol], a);
                atomicAdd(&neg_sum[jcol], b);
            }
        }
    }
}

// ---------------- per-row finalize: k_sims (fp32, float4 loads) ------------
__global__ void finalize_k(const float* __restrict__ q, const float* __restrict__ kmat,
                           const int* __restrict__ y, const int* __restrict__ counts,
                           const float* __restrict__ pos_sum, const float* __restrict__ neg_sum,
                           float* __restrict__ loss) {
    const int wave = threadIdx.x >> 6, lane = threadIdx.x & 63;
    const int i = blockIdx.x * 4 + wave;

    const float4* q4 = reinterpret_cast<const float4*>(q) + (size_t)i * 128;
    const float4* k4 = reinterpret_cast<const float4*>(kmat) + (size_t)i * KEXT * 128;
    float4 qa = q4[lane], qb = q4[lane + 64];

    float esum = 0.f;
    for (int kk = 0; kk < KEXT; kk++) {
        float4 ka = k4[(size_t)kk * 128 + lane];
        float4 kb = k4[(size_t)kk * 128 + lane + 64];
        float p = qa.x * ka.x;
        p = fmaf(qa.y, ka.y, p); p = fmaf(qa.z, ka.z, p); p = fmaf(qa.w, ka.w, p);
        p = fmaf(qb.x, kb.x, p); p = fmaf(qb.y, kb.y, p);
        p = fmaf(qb.z, kb.z, p); p = fmaf(qb.w, kb.w, p);
#pragma unroll
        for (int off = 1; off < 64; off <<= 1) p += __shfl_xor(p, off);
        esum += __expf(p * TAU_INV);
    }
    if (lane == 0) {
        float num = logf(esum + pos_sum[i]);
        float den = logf(neg_sum[i]);
        float cnt = (float)(counts[y[i]] - 1 + KEXT);  // same_class_counts, label-only
        loss[i] = -(num - den) / cnt;
    }
}

__global__ void reduce_k(const float* __restrict__ loss, float* __restrict__ out) {
    __shared__ float part[16];
    int tid = threadIdx.x;   // 1024 threads
    float s = 0.f;
    for (int i = tid; i < N; i += 1024) s += loss[i];
#pragma unroll
    for (int off = 1; off < 64; off <<= 1) s += __shfl_xor(s, off);
    if ((tid & 63) == 0) part[tid >> 6] = s;
    __syncthreads();
    if (tid < 16) {
        float v = part[tid];
#pragma unroll
        for (int off = 1; off < 16; off <<= 1) v += __shfl_xor(v, off);
        if (tid == 0) out[0] = v / (float)N;
    }
}

// ---------------- launch ----------------
extern "C" void kernel_launch(void* const* d_in, const int* in_sizes, int n_in,
                              void* d_out, int out_size, void* d_ws, size_t ws_size,
                              hipStream_t stream) {
    const float* q    = (const float*)d_in[0];
    const float* kmat = (const float*)d_in[1];
    const int*   y    = (const int*)d_in[2];
    float* out = (float*)d_out;

    char* ws = (char*)d_ws;
    uint32_t* qf8  = (uint32_t*)ws;                 // 4 MB: packed fp8 fragments
    int*   counts  = (int*)  (ws + 4194304);        // 1000 ints
    float* invc    = (float*)(ws + 4198400);        // 1000 floats
    float* pos     = (float*)(ws + 4202496);        // N floats
    float* neg     = (float*)(ws + 4235264);        // N floats
    float* loss    = (float*)(ws + 4268032);        // N floats

    prep_k    <<<1 + (N * 32) / 256, 256, 0, stream>>>(q, y, qf8, counts, invc, pos, neg);
    gemm_k    <<<NBLK, 256, 0, stream>>>(qf8, y, invc, pos, neg);
    finalize_k<<<N / 4, 256, 0, stream>>>(q, kmat, y, counts, pos, neg, loss);
    reduce_k  <<<1, 1024, 0, stream>>>(loss, out);
}

// Round 8
// 329.921 us; speedup vs baseline: 1.3975x; 1.0735x over previous
//
#include <hip/hip_runtime.h>
#include <hip/hip_fp8.h>
#include <stdint.h>

// Problem constants (fixed by reference setup_inputs)
constexpr int N    = 8192;
constexpr int D    = 512;
constexpr int KEXT = 8;
constexpr int NCLS = 1000;
#define TAU_INV  14.285714285714285714f   // 1/0.07
#define SQRT_TI  3.7796447300922722f      // sqrt(1/0.07); folded into packed fp8

typedef long   long2_t __attribute__((ext_vector_type(2)));  // 16B = 2 fp8 MFMA operands
typedef float  f32x4   __attribute__((ext_vector_type(4)));

typedef __attribute__((address_space(1))) void gvoid;
typedef __attribute__((address_space(3))) void lvoid;

__device__ __forceinline__ uint32_t pack4_e4m3(float a, float b, float c, float d) {
    __hip_fp8_e4m3 A(a), B(b), C(c), D(d);   // OCP e4m3fn on gfx950
    return (uint32_t)A.__x | ((uint32_t)B.__x << 8) |
           ((uint32_t)C.__x << 16) | ((uint32_t)D.__x << 24);
}

// ---------------- fused prep: histogram + fp8 fragment-packing of q --------
// qf8 layout (validated R7, absmax 0.0): 16B granule slot = (t*512 + ks2*64
// + quad*16 + l15), t=16-row tile, ks2=64-wide K-macrostep. Bytes [0..8) hold
// q[t*16+l15][ks2*64+quad*8 ..+8)*SQRT_TI, bytes [8..16) the +32 window.
// Band ib (8 tiles) is a CONTIGUOUS 64KB region -> linear LDS DMA in gemm.
// Also emits invy[j] = 1/count[y[j]] for direct column gathers.
__global__ void prep_k(const float* __restrict__ q, const int* __restrict__ y,
                       uint32_t* __restrict__ qf8, int* __restrict__ counts,
                       float* __restrict__ invy, float* __restrict__ pos,
                       float* __restrict__ neg) {
    const int b = blockIdx.x, tid = threadIdx.x;
    if (b == 0) {
        __shared__ int h[NCLS];
        for (int i = tid; i < NCLS; i += 256) h[i] = 0;
        __syncthreads();
        for (int i = tid; i < N; i += 256) atomicAdd(&h[y[i]], 1);
        __syncthreads();
        for (int i = tid; i < NCLS; i += 256) counts[i] = h[i];
        for (int i = tid; i < N; i += 256) invy[i] = 1.0f / (float)h[y[i]];
        return;
    }
    const int gid = (b - 1) * 256 + tid;     // over N*32 granules
    const int row = gid >> 5;                // source row of q
    const int c   = gid & 31;                // granule within row
    const int ks2 = c >> 2, quad = c & 3;
    const float* src = q + (size_t)row * D + ks2 * 64 + quad * 8;
    float4 v0 = *reinterpret_cast<const float4*>(src);
    float4 v1 = *reinterpret_cast<const float4*>(src + 4);
    float4 v2 = *reinterpret_cast<const float4*>(src + 32);
    float4 v3 = *reinterpret_cast<const float4*>(src + 36);
    uint4 o;
    o.x = pack4_e4m3(v0.x * SQRT_TI, v0.y * SQRT_TI, v0.z * SQRT_TI, v0.w * SQRT_TI);
    o.y = pack4_e4m3(v1.x * SQRT_TI, v1.y * SQRT_TI, v1.z * SQRT_TI, v1.w * SQRT_TI);
    o.z = pack4_e4m3(v2.x * SQRT_TI, v2.y * SQRT_TI, v2.z * SQRT_TI, v2.w * SQRT_TI);
    o.w = pack4_e4m3(v3.x * SQRT_TI, v3.y * SQRT_TI, v3.z * SQRT_TI, v3.w * SQRT_TI);
    const int t = row >> 4, l15 = row & 15;
    reinterpret_cast<uint4*>(qf8)[(size_t)t * 512 + ks2 * 64 + quad * 16 + l15] = o;
    if (gid < N) { pos[gid] = 0.f; neg[gid] = 0.f; }
}

// ---------------- band-sweep GEMM (q @ q^T) + fused contrastive epilogue ---
// 512 blocks = 64 row-bands x 8 col-chunks of 1024. A-band (64KB fp8) DMA'd
// to LDS once; B streamed once per block via coalesced packed-fragment loads
// (qf8 = 4MB, L2-resident). Row pos/neg sums accumulate in REGISTERS across
// the 8-subtile sweep, combined through LDS at the end: 256 atomics/block
// (131K total, was 1.58M) -> atomic write-back collapses.
__global__ __launch_bounds__(256, 2) void gemm_k(
        const uint32_t* __restrict__ qf8,
        const int* __restrict__ y,
        const float* __restrict__ invy,
        float* __restrict__ pos_sum,
        float* __restrict__ neg_sum) {
    __shared__ long2_t Asl[4096];       // 64KB: band's 8 tiles x 512 granules
    __shared__ int   yR[128];           // band labels
    __shared__ float redP[2][128];      // column-half partials
    __shared__ float redN[2][128];

    const int tid  = threadIdx.x;
    const int wave = tid >> 6;
    const int lane = tid & 63;
    const int quad = lane >> 4;
    const int l15  = lane & 15;

    const int ib     = blockIdx.x >> 3;       // row band 0..63
    const int jchunk = blockIdx.x & 7;        // 1024-col chunk
    const int ibase  = ib * 128;

    // ---- DMA A-band into LDS: pure linear 64KB copy ----
    {
        const uint32_t* src = qf8 + (size_t)ib * 16384;   // 4096 granules
#pragma unroll
        for (int it = 0; it < 16; it++) {
            const int idx = it * 256 + tid;
            __builtin_amdgcn_global_load_lds((gvoid*)(src + idx * 4),
                                             (lvoid*)(Asl + idx), 16, 0, 0);
        }
    }
    if (tid < 128) yR[tid] = y[ibase + tid];
    __syncthreads();   // DMA drained (compiler emits vmcnt(0) before barrier)

    // wave position: 2x2 waves over each 128x128 subtile
    const int wr = (wave >> 1) * 64;
    const int wc = (wave & 1) * 64;
    const int half = wave & 1;

    // per-lane row metadata and register row-sums
    int yi[16];
#pragma unroll
    for (int mi = 0; mi < 4; mi++)
#pragma unroll
        for (int r = 0; r < 4; r++)
            yi[mi * 4 + r] = yR[wr + mi * 16 + quad * 4 + r];

    float posp[16], negp[16];
#pragma unroll
    for (int e = 0; e < 16; e++) { posp[e] = 0.f; negp[e] = 0.f; }

    const long2_t* fb = reinterpret_cast<const long2_t*>(qf8);
    // B fragment pointers for subtile 0 of this chunk
    const long2_t* pB[4];
#pragma unroll
    for (int m = 0; m < 4; m++)
        pB[m] = fb + (size_t)(jchunk * 64 + (wc >> 4) + m) * 512 + lane;

    const int tA = wr >> 4;                  // local A tile base (0 or 4)

    for (int jt = 0; jt < 8; jt++) {
        const int j0 = jchunk * 1024 + jt * 128;

        // column metadata
        int   yjv[4];
        float icj[4];
#pragma unroll
        for (int mj = 0; mj < 4; mj++) {
            int jc = j0 + wc + mj * 16 + l15;
            yjv[mj] = y[jc];
            icj[mj] = invy[jc];
        }

        f32x4 acc[4][4];
#pragma unroll
        for (int a = 0; a < 4; a++)
#pragma unroll
            for (int c = 0; c < 4; c++) acc[a][c] = (f32x4)0.0f;

        // K-loop: 8 macro-steps of K=64, register double-buffered
        long2_t af[2][4], bf[2][4];
#pragma unroll
        for (int m = 0; m < 4; m++) {
            af[0][m] = Asl[(tA + m) * 512 + lane];
            bf[0][m] = pB[m][0];
        }
#pragma unroll
        for (int ks2 = 0; ks2 < 8; ks2++) {
            const int cur = ks2 & 1, nxt = cur ^ 1;
            if (ks2 < 7) {
#pragma unroll
                for (int m = 0; m < 4; m++) {
                    af[nxt][m] = Asl[(tA + m) * 512 + (ks2 + 1) * 64 + lane];
                    bf[nxt][m] = pB[m][(ks2 + 1) * 64];
                }
            }
#pragma unroll
            for (int mi = 0; mi < 4; mi++)
#pragma unroll
                for (int mj = 0; mj < 4; mj++)
                    acc[mi][mj] = __builtin_amdgcn_mfma_f32_16x16x32_fp8_fp8(
                        af[cur][mi].x, bf[cur][mj].x, acc[mi][mj], 0, 0, 0);
#pragma unroll
            for (int mi = 0; mi < 4; mi++)
#pragma unroll
                for (int mj = 0; mj < 4; mj++)
                    acc[mi][mj] = __builtin_amdgcn_mfma_f32_16x16x32_fp8_fp8(
                        af[cur][mi].y, bf[cur][mj].y, acc[mi][mj], 0, 0, 0);
        }
#pragma unroll
        for (int m = 0; m < 4; m++) pB[m] += 4096;   // next 128 cols (8 tiles)

        // fused epilogue: acc holds sim/tau (sqrt(1/tau) folded into qf8)
#pragma unroll
        for (int mi = 0; mi < 4; mi++) {
#pragma unroll
            for (int r = 0; r < 4; r++) {
                const int e    = mi * 4 + r;
                const int irow = ibase + wr + mi * 16 + quad * 4 + r;
                const int myi  = yi[e];
                float ps = 0.f, ns = 0.f;
#pragma unroll
                for (int mj = 0; mj < 4; mj++) {
                    const int jcol = j0 + wc + mj * 16 + l15;   // C/D: col = lane&15
                    float a    = acc[mi][mj][r];
                    float ex   = __expf(a);
                    bool  nz   = (a != 0.0f);                   // faithful masked_fill(x==0,-inf)
                    bool  same = (myi == yjv[mj]);
                    ps += (same && (irow != jcol) && nz) ? ex : 0.0f;
                    ns += (!same && nz) ? ex * icj[mj] : 0.0f;
                }
                posp[e] += ps;
                negp[e] += ns;
            }
        }
    }

    // ---- commit: 16-lane reduce -> LDS column-half combine -> 256 atomics ----
#pragma unroll
    for (int mi = 0; mi < 4; mi++) {
#pragma unroll
        for (int r = 0; r < 4; r++) {
            const int e = mi * 4 + r;
            float ps = posp[e], ns = negp[e];
#pragma unroll
            for (int off = 1; off < 16; off <<= 1) {
                ps += __shfl_xor(ps, off);
                ns += __shfl_xor(ns, off);
            }
            if (l15 == 0) {
                const int il = wr + mi * 16 + quad * 4 + r;
                redP[half][il] = ps;
                redN[half][il] = ns;
            }
        }
    }
    __syncthreads();
    if (tid < 128) {
        atomicAdd(&pos_sum[ibase + tid], redP[0][tid] + redP[1][tid]);
    } else if (tid < 256) {
        const int il = tid - 128;
        atomicAdd(&neg_sum[ibase + il], redN[0][il] + redN[1][il]);
    }
}

// ---------------- per-row finalize: k_sims (fp32, float4 loads) ------------
__global__ void finalize_k(const float* __restrict__ q, const float* __restrict__ kmat,
                           const int* __restrict__ y, const int* __restrict__ counts,
                           const float* __restrict__ pos_sum, const float* __restrict__ neg_sum,
                           float* __restrict__ loss) {
    const int wave = threadIdx.x >> 6, lane = threadIdx.x & 63;
    const int i = blockIdx.x * 4 + wave;

    const float4* q4 = reinterpret_cast<const float4*>(q) + (size_t)i * 128;
    const float4* k4 = reinterpret_cast<const float4*>(kmat) + (size_t)i * KEXT * 128;
    float4 qa = q4[lane], qb = q4[lane + 64];

    float esum = 0.f;
    for (int kk = 0; kk < KEXT; kk++) {
        float4 ka = k4[(size_t)kk * 128 + lane];
        float4 kb = k4[(size_t)kk * 128 + lane + 64];
        float p = qa.x * ka.x;
        p = fmaf(qa.y, ka.y, p); p = fmaf(qa.z, ka.z, p); p = fmaf(qa.w, ka.w, p);
        p = fmaf(qb.x, kb.x, p); p = fmaf(qb.y, kb.y, p);
        p = fmaf(qb.z, kb.z, p); p = fmaf(qb.w, kb.w, p);
#pragma unroll
        for (int off = 1; off < 64; off <<= 1) p += __shfl_xor(p, off);
        esum += __expf(p * TAU_INV);
    }
    if (lane == 0) {
        float num = logf(esum + pos_sum[i]);
        float den = logf(neg_sum[i]);
        float cnt = (float)(counts[y[i]] - 1 + KEXT);  // same_class_counts, label-only
        loss[i] = -(num - den) / cnt;
    }
}

__global__ void reduce_k(const float* __restrict__ loss, float* __restrict__ out) {
    __shared__ float part[16];
    int tid = threadIdx.x;   // 1024 threads
    float s = 0.f;
    for (int i = tid; i < N; i += 1024) s += loss[i];
#pragma unroll
    for (int off = 1; off < 64; off <<= 1) s += __shfl_xor(s, off);
    if ((tid & 63) == 0) part[tid >> 6] = s;
    __syncthreads();
    if (tid < 16) {
        float v = part[tid];
#pragma unroll
        for (int off = 1; off < 16; off <<= 1) v += __shfl_xor(v, off);
        if (tid == 0) out[0] = v / (float)N;
    }
}

// ---------------- launch ----------------
extern "C" void kernel_launch(void* const* d_in, const int* in_sizes, int n_in,
                              void* d_out, int out_size, void* d_ws, size_t ws_size,
                              hipStream_t stream) {
    const float* q    = (const float*)d_in[0];
    const float* kmat = (const float*)d_in[1];
    const int*   y    = (const int*)d_in[2];
    float* out = (float*)d_out;

    char* ws = (char*)d_ws;
    uint32_t* qf8  = (uint32_t*)ws;                 // 4 MB: packed fp8 fragments
    int*   counts  = (int*)  (ws + 4194304);        // 1000 ints
    float* invy    = (float*)(ws + 4198400);        // N floats: 1/count[y[j]]
    float* pos     = (float*)(ws + 4231168);        // N floats
    float* neg     = (float*)(ws + 4263936);        // N floats
    float* loss    = (float*)(ws + 4296704);        // N floats

    prep_k    <<<1 + (N * 32) / 256, 256, 0, stream>>>(q, y, qf8, counts, invy, pos, neg);
    gemm_k    <<<512, 256, 0, stream>>>(qf8, y, invy, pos, neg);
    finalize_k<<<N / 4, 256, 0, stream>>>(q, kmat, y, counts, pos, neg, loss);
    reduce_k  <<<1, 1024, 0, stream>>>(loss, out);
}